// Round 12
// baseline (150.780 us; speedup 1.0000x reference)
//
#include <hip/hip_runtime.h>
#include <math.h>

#define N_VEC 65536
#define D 64
#define K 1024
#define VQ_EPS 1e-10f

typedef __attribute__((ext_vector_type(8))) short s16x8;   // 8 bf16 = 4 VGPR
typedef __attribute__((ext_vector_type(4))) float f32x4;   // MFMA acc

#define MFMA(a, b, c) __builtin_amdgcn_mfma_f32_16x16x32_bf16((a), (b), (c), 0, 0, 0)

__device__ __forceinline__ unsigned short bf16_rne(float f) {
    unsigned u = __float_as_uint(f);
    u += 0x7fff + ((u >> 16) & 1);
    return (unsigned short)(u >> 16);
}
__device__ __forceinline__ float bf16_f32(unsigned short h) {
    return __uint_as_float(((unsigned)h) << 16);
}

// ---------------------------------------------------------------------------
// Kernel A: pack embeddings into MFMA-fragment order (unchanged layout:
// chunk = ct*16 + g*4 + bg; bg: 0=hi k0-31, 1=hi k32-63, 2=lo k0-31,
// 3=lo k32-63; slot q*16+c = 8 bf16 of code g*16+c), fp32 norms, zero
// counts, and init the per-vector best64 keys to 0 (any real key > 0).
// ---------------------------------------------------------------------------
__global__ void pack_e_kernel(const float* __restrict__ emb,
                              uint4* __restrict__ ep4,
                              float* __restrict__ enorm,
                              int* __restrict__ counts,
                              unsigned long long* __restrict__ best64) {
    int gid = blockIdx.x * 256 + threadIdx.x;      // 0..4095
    int code = gid >> 2, tq = gid & 3;             // tq: k-quarter (16 elems)
    const float* row = emb + (size_t)code * D + tq * 16;
    unsigned int hi[8], lo[8];
    float nrm = 0.f;
#pragma unroll
    for (int i = 0; i < 4; ++i) {
        float4 v = *reinterpret_cast<const float4*>(row + i * 4);
        nrm += v.x * v.x + v.y * v.y + v.z * v.z + v.w * v.w;
        float f[4] = {v.x, v.y, v.z, v.w};
        unsigned short hh[4], ll[4];
#pragma unroll
        for (int j = 0; j < 4; ++j) {
            hh[j] = bf16_rne(f[j]);
            ll[j] = bf16_rne(f[j] - bf16_f32(hh[j]));
        }
        hi[i * 2 + 0] = (unsigned)hh[0] | ((unsigned)hh[1] << 16);
        hi[i * 2 + 1] = (unsigned)hh[2] | ((unsigned)hh[3] << 16);
        lo[i * 2 + 0] = (unsigned)ll[0] | ((unsigned)ll[1] << 16);
        lo[i * 2 + 1] = (unsigned)ll[2] | ((unsigned)ll[3] << 16);
    }
    const int ct = code >> 6, g = (code >> 4) & 3, c = code & 15;
#pragma unroll
    for (int h = 0; h < 2; ++h) {
        int gran = 2 * tq + h;               // 0..7
        int bg = gran >> 2, q = gran & 3;
        ep4[(size_t)(ct * 16 + g * 4 + bg) * 64 + q * 16 + c] =
            make_uint4(hi[h * 4], hi[h * 4 + 1], hi[h * 4 + 2], hi[h * 4 + 3]);
        int granl = 8 + gran;                // lo: bg 2..3
        bg = granl >> 2; q = granl & 3;
        ep4[(size_t)(ct * 16 + g * 4 + bg) * 64 + q * 16 + c] =
            make_uint4(lo[h * 4], lo[h * 4 + 1], lo[h * 4 + 2], lo[h * 4 + 3]);
    }
    nrm += __shfl_xor(nrm, 1, 64);
    nrm += __shfl_xor(nrm, 2, 64);
    if (tq == 0) enorm[code] = nrm;
    if (gid < K) counts[gid] = 0;
    // init best64: 65536 keys / 4096 threads = 16 each
    unsigned long long* b = best64 + (size_t)gid * 16;
#pragma unroll
    for (int i = 0; i < 16; ++i) b[i] = 0ULL;
}

// ---------------------------------------------------------------------------
// Kernel B: barrier-free streaming MFMA VQ.
//  - grid 2048 = (vb groups of 64 vectors) x (2 K-halves of 512 codes).
//  - Wave owns 16 vectors (A = 4 named s16x8, 16 VGPRs). B-frags stream
//    DIRECTLY from the L2-resident packed codebook to VGPRs (coalesced
//    ep4[chunk*64+lane], 1 KB/instr). NO LDS, NO DMA, NO __syncthreads:
//    waves fully independent; compiler does fine-grained vmcnt pipelining.
//  - acc init = -enc/2 (C operand); argMAX of score = dot - enc/2
//    (dist = -2*score: exact monotone map, exact tie equivalence).
//  - Cross-block combine: per-vector packed u64 atomicMax with key =
//    (monotone_u32(score) << 32) | (1023 - code): max key == max score,
//    score-tie -> smaller code. Bit-exact same winner as single-block.
// C-layout: col(code)=lane&15, row(vec)=(lane>>4)*4+reg (m89-verified).
// ---------------------------------------------------------------------------
__global__ void __launch_bounds__(256, 6)
vq_kernel(const float* __restrict__ x,
          const uint4* __restrict__ ep4,
          const float* __restrict__ enormp,
          unsigned long long* __restrict__ best64) {
    const int t    = threadIdx.x;
    const int w    = t >> 6;
    const int lane = t & 63;
    const int q    = lane >> 4;
    const int c    = lane & 15;
    const int bid  = blockIdx.x;
    const int kh   = bid & 1;                 // K-half: codes [kh*512, +512)
    const int vb   = (bid >> 1) * 64;

    // ---- A-frags: 16 vectors/wave, bf16 hi/lo (16 VGPRs total) ----
    s16x8 Ah0, Ah1, Al0, Al1;
#define LOAD_A(h, AH, AL)                                                      \
    {                                                                          \
        const float* xr = x + (size_t)(vb + w * 16 + c) * D + (h) * 32 + q * 8;\
        float4 u0 = *reinterpret_cast<const float4*>(xr);                      \
        float4 u1 = *reinterpret_cast<const float4*>(xr + 4);                  \
        float f[8] = {u0.x, u0.y, u0.z, u0.w, u1.x, u1.y, u1.z, u1.w};         \
        s16x8 hiv, lov;                                                        \
        _Pragma("unroll") for (int j = 0; j < 8; ++j) {                        \
            unsigned short hb = bf16_rne(f[j]);                                \
            hiv[j] = (short)hb;                                                \
            lov[j] = (short)bf16_rne(f[j] - bf16_f32(hb));                     \
        }                                                                      \
        AH = hiv; AL = lov;                                                    \
    }
    LOAD_A(0, Ah0, Al0)
    LOAD_A(1, Ah1, Al1)
#undef LOAD_A

    float best[4];
    int   bk_[4];
#pragma unroll
    for (int s = 0; s < 4; ++s) { best[s] = -3.4e38f; bk_[s] = 0; }

    const uint4* epb = ep4 + (size_t)(kh * 128) * 64;   // this half's chunks
    const float* enb = enormp + kh * 512;

#pragma unroll 4
    for (int cg = 0; cg < 32; ++cg) {          // 16 codes per cg
        s16x8 Bh0 = *reinterpret_cast<const s16x8*>(&epb[(cg * 4 + 0) * 64 + lane]);
        s16x8 Bh1 = *reinterpret_cast<const s16x8*>(&epb[(cg * 4 + 1) * 64 + lane]);
        s16x8 Bl0 = *reinterpret_cast<const s16x8*>(&epb[(cg * 4 + 2) * 64 + lane]);
        s16x8 Bl1 = *reinterpret_cast<const s16x8*>(&epb[(cg * 4 + 3) * 64 + lane]);
        float enc = enb[cg * 16 + c];

        const float e2 = -0.5f * enc;
        f32x4 acc = (f32x4){e2, e2, e2, e2};
        acc = MFMA(Ah0, Bh0, acc);
        acc = MFMA(Ah1, Bh1, acc);
        acc = MFMA(Ah0, Bl0, acc);
        acc = MFMA(Ah1, Bl1, acc);
        acc = MFMA(Al0, Bh0, acc);
        acc = MFMA(Al1, Bh1, acc);

        const int codeG = kh * 512 + cg * 16 + c;
#pragma unroll
        for (int r = 0; r < 4; ++r) {
            if (acc[r] > best[r]) { best[r] = acc[r]; bk_[r] = codeG; }
        }
    }

    // ---- reduce over the 16 code-columns (max score; tie -> smaller idx) ----
#pragma unroll
    for (int m = 1; m <= 8; m <<= 1)
#pragma unroll
        for (int s = 0; s < 4; ++s) {
            float ob = __shfl_xor(best[s], m, 64);
            int   ok = __shfl_xor(bk_[s], m, 64);
            if (ob > best[s] || (ob == best[s] && ok < bk_[s])) {
                best[s] = ob; bk_[s] = ok;
            }
        }
    if (c == 0) {
#pragma unroll
        for (int r = 0; r < 4; ++r) {
            unsigned u = __float_as_uint(best[r]);
            u = ((int)u < 0) ? ~u : (u | 0x80000000u);   // monotone fp32->u32
            unsigned long long key =
                ((unsigned long long)u << 32) | (unsigned)(1023 - bk_[r]);
            atomicMax(&best64[vb + w * 16 + q * 4 + r], key);
        }
    }
}

// ---------------------------------------------------------------------------
// Kernel C: gather winners -> out (exact fp32 rows) + histogram counts.
// 1024 blocks x 256 thr; 4 threads per vector.
// ---------------------------------------------------------------------------
__global__ void gather_kernel(const unsigned long long* __restrict__ best64,
                              const float* __restrict__ emb,
                              int* __restrict__ counts,
                              float* __restrict__ out) {
    int t = threadIdx.x;
    int vec = blockIdx.x * 64 + (t >> 2), part = t & 3;
    unsigned long long kv = best64[vec];
    int code = 1023 - (int)(kv & 0xFFFFFFFFu);
    if (part == 0) atomicAdd(&counts[code], 1);
    const float4* src = reinterpret_cast<const float4*>(emb + (size_t)code * D) + part * 4;
    float4* dst = reinterpret_cast<float4*>(out + (size_t)vec * D) + part * 4;
#pragma unroll
    for (int j = 0; j < 4; ++j) dst[j] = src[j];
}

// ---------------------------------------------------------------------------
// Kernel D: perplexity = exp(-sum p log(p+eps)), p = counts/N. 256 threads.
// ---------------------------------------------------------------------------
__global__ void perplexity_kernel(const int* __restrict__ counts,
                                  float* __restrict__ outp) {
    int t = threadIdx.x;
    float s = 0.f;
#pragma unroll
    for (int i = 0; i < 4; ++i) {
        float p = (float)counts[t + i * 256] * (1.0f / (float)N_VEC);
        s += p * logf(p + VQ_EPS);
    }
#pragma unroll
    for (int m = 1; m < 64; m <<= 1) s += __shfl_xor(s, m, 64);
    __shared__ float ws[4];
    if ((t & 63) == 0) ws[t >> 6] = s;
    __syncthreads();
    if (t == 0) *outp = expf(-(ws[0] + ws[1] + ws[2] + ws[3]));
}

// ---------------------------------------------------------------------------
extern "C" void kernel_launch(void* const* d_in, const int* in_sizes, int n_in,
                              void* d_out, int out_size, void* d_ws, size_t ws_size,
                              hipStream_t stream) {
    const float* x   = (const float*)d_in[0];   // [65536, 64] fp32
    const float* emb = (const float*)d_in[1];   // [1024, 64] fp32
    float* out = (float*)d_out;                 // 4194304 quantized + 1 perplexity

    uint4*  ep     = (uint4*)d_ws;                                     // 256 KB packed
    float*  enorm  = (float*)((char*)d_ws + (size_t)K * 128 * 2);      // 4 KB
    int*    counts = (int*)((char*)enorm + K * sizeof(float));         // 4 KB
    unsigned long long* best64 =
        (unsigned long long*)((char*)counts + K * sizeof(int));        // 512 KB

    pack_e_kernel<<<16, 256, 0, stream>>>(emb, ep, enorm, counts, best64);
    vq_kernel<<<2048, 256, 0, stream>>>(x, ep, enorm, best64);
    gather_kernel<<<1024, 256, 0, stream>>>(best64, emb, counts, out);
    perplexity_kernel<<<1, 256, 0, stream>>>(counts, out + (size_t)N_VEC * D);
}

// Round 13
// 132.751 us; speedup vs baseline: 1.1358x; 1.1358x over previous
//
#include <hip/hip_runtime.h>
#include <math.h>

#define N_VEC 65536
#define D 64
#define K 1024
#define VQ_EPS 1e-10f

typedef __attribute__((ext_vector_type(8))) short s16x8;   // 8 bf16 = 4 VGPR
typedef __attribute__((ext_vector_type(4))) float f32x4;   // MFMA acc

#define MFMA(a, b, c) __builtin_amdgcn_mfma_f32_16x16x32_bf16((a), (b), (c), 0, 0, 0)

__device__ __forceinline__ unsigned short bf16_rne(float f) {
    unsigned u = __float_as_uint(f);
    u += 0x7fff + ((u >> 16) & 1);
    return (unsigned short)(u >> 16);
}
__device__ __forceinline__ float bf16_f32(unsigned short h) {
    return __uint_as_float(((unsigned)h) << 16);
}

// ---------------------------------------------------------------------------
// Kernel A (layout unchanged, benched correct): pack embeddings into
// MFMA-fragment order. Chunk = ct*16 + g*4 + bg (bg: 0=hi k0-31, 1=hi
// k32-63, 2=lo k0-31, 3=lo k32-63); slot q*16+c = 8 bf16 of code g*16+c.
// fp32 norms + zero counts.
// ---------------------------------------------------------------------------
__global__ void pack_e_kernel(const float* __restrict__ emb,
                              uint4* __restrict__ ep4,
                              float* __restrict__ enorm,
                              int* __restrict__ counts) {
    int gid = blockIdx.x * 256 + threadIdx.x;      // 0..4095
    int code = gid >> 2, tq = gid & 3;             // tq: k-quarter (16 elems)
    const float* row = emb + (size_t)code * D + tq * 16;
    unsigned int hi[8], lo[8];
    float nrm = 0.f;
#pragma unroll
    for (int i = 0; i < 4; ++i) {
        float4 v = *reinterpret_cast<const float4*>(row + i * 4);
        nrm += v.x * v.x + v.y * v.y + v.z * v.z + v.w * v.w;
        float f[4] = {v.x, v.y, v.z, v.w};
        unsigned short hh[4], ll[4];
#pragma unroll
        for (int j = 0; j < 4; ++j) {
            hh[j] = bf16_rne(f[j]);
            ll[j] = bf16_rne(f[j] - bf16_f32(hh[j]));
        }
        hi[i * 2 + 0] = (unsigned)hh[0] | ((unsigned)hh[1] << 16);
        hi[i * 2 + 1] = (unsigned)hh[2] | ((unsigned)hh[3] << 16);
        lo[i * 2 + 0] = (unsigned)ll[0] | ((unsigned)ll[1] << 16);
        lo[i * 2 + 1] = (unsigned)ll[2] | ((unsigned)ll[3] << 16);
    }
    const int ct = code >> 6, g = (code >> 4) & 3, c = code & 15;
#pragma unroll
    for (int h = 0; h < 2; ++h) {
        int gran = 2 * tq + h;               // 0..7
        int bg = gran >> 2, q = gran & 3;
        ep4[(size_t)(ct * 16 + g * 4 + bg) * 64 + q * 16 + c] =
            make_uint4(hi[h * 4], hi[h * 4 + 1], hi[h * 4 + 2], hi[h * 4 + 3]);
        int granl = 8 + gran;                // lo: bg 2..3
        bg = granl >> 2; q = granl & 3;
        ep4[(size_t)(ct * 16 + g * 4 + bg) * 64 + q * 16 + c] =
            make_uint4(lo[h * 4], lo[h * 4 + 1], lo[h * 4 + 2], lo[h * 4 + 3]);
    }
    nrm += __shfl_xor(nrm, 1, 64);
    nrm += __shfl_xor(nrm, 2, 64);
    if (tq == 0) enorm[code] = nrm;
    if (gid < K) counts[gid] = 0;
}

// ---------------------------------------------------------------------------
// Kernel B: streaming MFMA VQ, in-block K-split (no gather pass).
//  - Block = 512 thr = 8 waves: wave (wp, kh) — wp=vector group (16 vecs),
//    kh=K-half (512 codes). No barriers in the K-loop; B-frags stream
//    directly from the L2-resident packed codebook (coalesced 1 KB/instr).
//  - acc init = -enc/2 (C operand); argMAX of score = dot - enc/2
//    (dist = -2*score: exact monotone map, exact tie equivalence).
//  - End: kh=0 publishes packed u64 keys (monotone-score : 1023-code) to
//    LDS; one barrier; kh=1 combines (bit-exact first-occurrence ties),
//    counts atomics; barrier; all threads write output rows directly.
//  - Grid 1024 x 8 waves = 8192 waves = full CU capacity; dispatches 4 -> 3.
// C-layout: col(code)=lane&15, row(vec)=(lane>>4)*4+reg (m89-verified).
// ---------------------------------------------------------------------------
__global__ void __launch_bounds__(512, 8)
vq_kernel(const float* __restrict__ x,
          const float* __restrict__ emb,
          const uint4* __restrict__ ep4,
          const float* __restrict__ enormp,
          int* __restrict__ counts,
          float* __restrict__ out) {
    __shared__ unsigned long long keys[64];
    __shared__ int bks[64];

    const int t    = threadIdx.x;
    const int w    = t >> 6;
    const int wp   = w >> 1;                  // vector group 0..3
    const int kh   = w & 1;                   // K-half
    const int lane = t & 63;
    const int q    = lane >> 4;
    const int c    = lane & 15;
    const int vb   = blockIdx.x * 64;

    // ---- A-frags: 16 vectors/wave, bf16 hi/lo (16 VGPRs total) ----
    s16x8 Ah0, Ah1, Al0, Al1;
#define LOAD_A(h, AH, AL)                                                      \
    {                                                                          \
        const float* xr = x + (size_t)(vb + wp * 16 + c) * D + (h) * 32 + q * 8;\
        float4 u0 = *reinterpret_cast<const float4*>(xr);                      \
        float4 u1 = *reinterpret_cast<const float4*>(xr + 4);                  \
        float f[8] = {u0.x, u0.y, u0.z, u0.w, u1.x, u1.y, u1.z, u1.w};         \
        s16x8 hiv, lov;                                                        \
        _Pragma("unroll") for (int j = 0; j < 8; ++j) {                        \
            unsigned short hb = bf16_rne(f[j]);                                \
            hiv[j] = (short)hb;                                                \
            lov[j] = (short)bf16_rne(f[j] - bf16_f32(hb));                     \
        }                                                                      \
        AH = hiv; AL = lov;                                                    \
    }
    LOAD_A(0, Ah0, Al0)
    LOAD_A(1, Ah1, Al1)
#undef LOAD_A

    float best[4];
    int   bk_[4];
#pragma unroll
    for (int s = 0; s < 4; ++s) { best[s] = -3.4e38f; bk_[s] = 0; }

    const uint4* epb = ep4 + (size_t)(kh * 128) * 64;   // this half's chunks
    const float* enb = enormp + kh * 512;

#pragma unroll 4
    for (int cg = 0; cg < 32; ++cg) {          // 16 codes per cg
        s16x8 Bh0 = *reinterpret_cast<const s16x8*>(&epb[(cg * 4 + 0) * 64 + lane]);
        s16x8 Bh1 = *reinterpret_cast<const s16x8*>(&epb[(cg * 4 + 1) * 64 + lane]);
        s16x8 Bl0 = *reinterpret_cast<const s16x8*>(&epb[(cg * 4 + 2) * 64 + lane]);
        s16x8 Bl1 = *reinterpret_cast<const s16x8*>(&epb[(cg * 4 + 3) * 64 + lane]);
        float enc = enb[cg * 16 + c];

        const float e2 = -0.5f * enc;
        f32x4 acc = (f32x4){e2, e2, e2, e2};
        acc = MFMA(Ah0, Bh0, acc);
        acc = MFMA(Ah1, Bh1, acc);
        acc = MFMA(Ah0, Bl0, acc);
        acc = MFMA(Ah1, Bl1, acc);
        acc = MFMA(Al0, Bh0, acc);
        acc = MFMA(Al1, Bh1, acc);

        const int codeG = kh * 512 + cg * 16 + c;
#pragma unroll
        for (int r = 0; r < 4; ++r) {
            if (acc[r] > best[r]) { best[r] = acc[r]; bk_[r] = codeG; }
        }
    }

    // ---- reduce over the 16 code-columns (max score; tie -> smaller idx) ----
#pragma unroll
    for (int m = 1; m <= 8; m <<= 1)
#pragma unroll
        for (int s = 0; s < 4; ++s) {
            float ob = __shfl_xor(best[s], m, 64);
            int   ok = __shfl_xor(bk_[s], m, 64);
            if (ob > best[s] || (ob == best[s] && ok < bk_[s])) {
                best[s] = ob; bk_[s] = ok;
            }
        }

    // packed key: (monotone_u32(score) << 32) | (1023 - code)
    unsigned long long mykey[4];
#pragma unroll
    for (int r = 0; r < 4; ++r) {
        unsigned u = __float_as_uint(best[r]);
        u = ((int)u < 0) ? ~u : (u | 0x80000000u);
        mykey[r] = ((unsigned long long)u << 32) | (unsigned)(1023 - bk_[r]);
    }

    if (kh == 0 && c == 0) {
#pragma unroll
        for (int r = 0; r < 4; ++r) keys[wp * 16 + q * 4 + r] = mykey[r];
    }
    __syncthreads();
    if (kh == 1 && c == 0) {
#pragma unroll
        for (int r = 0; r < 4; ++r) {
            int lv = wp * 16 + q * 4 + r;
            unsigned long long k0 = keys[lv];
            unsigned long long kw = (mykey[r] > k0) ? mykey[r] : k0;
            int code = 1023 - (int)(kw & 0xFFFFFFFFu);
            bks[lv] = code;
            atomicAdd(&counts[code], 1);
        }
    }
    __syncthreads();

    // ---- all 512 threads: write winning rows -> out (exact fp32) ----
    {
        int vec = t >> 3, part = t & 7;          // 8 threads per vector
        int kk = bks[vec];
        const float4* src = reinterpret_cast<const float4*>(emb + (size_t)kk * D) + part * 2;
        float4* dst = reinterpret_cast<float4*>(out + (size_t)(vb + vec) * D) + part * 2;
        dst[0] = src[0];
        dst[1] = src[1];
    }
}

// ---------------------------------------------------------------------------
// Kernel C: perplexity = exp(-sum p log(p+eps)), p = counts/N. 256 threads.
// ---------------------------------------------------------------------------
__global__ void perplexity_kernel(const int* __restrict__ counts,
                                  float* __restrict__ outp) {
    int t = threadIdx.x;
    float s = 0.f;
#pragma unroll
    for (int i = 0; i < 4; ++i) {
        float p = (float)counts[t + i * 256] * (1.0f / (float)N_VEC);
        s += p * logf(p + VQ_EPS);
    }
#pragma unroll
    for (int m = 1; m < 64; m <<= 1) s += __shfl_xor(s, m, 64);
    __shared__ float ws[4];
    if ((t & 63) == 0) ws[t >> 6] = s;
    __syncthreads();
    if (t == 0) *outp = expf(-(ws[0] + ws[1] + ws[2] + ws[3]));
}

// ---------------------------------------------------------------------------
extern "C" void kernel_launch(void* const* d_in, const int* in_sizes, int n_in,
                              void* d_out, int out_size, void* d_ws, size_t ws_size,
                              hipStream_t stream) {
    const float* x   = (const float*)d_in[0];   // [65536, 64] fp32
    const float* emb = (const float*)d_in[1];   // [1024, 64] fp32
    float* out = (float*)d_out;                 // 4194304 quantized + 1 perplexity

    uint4* ep     = (uint4*)d_ws;                                      // 256 KB packed
    float* enorm  = (float*)((char*)d_ws + (size_t)K * 128 * 2);       // 4 KB
    int*   counts = (int*)((char*)enorm + K * sizeof(float));          // 4 KB

    pack_e_kernel<<<16, 256, 0, stream>>>(emb, ep, enorm, counts);
    vq_kernel<<<N_VEC / 64, 512, 0, stream>>>(x, emb, ep, enorm, counts, out);
    perplexity_kernel<<<1, 256, 0, stream>>>(counts, out + (size_t)N_VEC * D);
}

// Round 14
// 132.582 us; speedup vs baseline: 1.1373x; 1.0013x over previous
//
#include <hip/hip_runtime.h>
#include <math.h>

#define N_VEC 65536
#define D 64
#define K 1024
#define VQ_EPS 1e-10f

typedef __attribute__((ext_vector_type(8))) short s16x8;   // 8 bf16 = 4 VGPR
typedef __attribute__((ext_vector_type(4))) float f32x4;   // MFMA acc

#define MFMA(a, b, c) __builtin_amdgcn_mfma_f32_16x16x32_bf16((a), (b), (c), 0, 0, 0)

__device__ __forceinline__ unsigned short bf16_rne(float f) {
    unsigned u = __float_as_uint(f);
    u += 0x7fff + ((u >> 16) & 1);
    return (unsigned short)(u >> 16);
}
__device__ __forceinline__ float bf16_f32(unsigned short h) {
    return __uint_as_float(((unsigned)h) << 16);
}

// ---------------------------------------------------------------------------
// Kernel A (layout unchanged, benched correct): pack embeddings into
// MFMA-fragment order. Chunk = ct*16 + g*4 + bg (bg: 0=hi k0-31, 1=hi
// k32-63, 2=lo k0-31, 3=lo k32-63); slot q*16+c = 8 bf16 of code g*16+c.
// fp32 norms + zero counts.
// ---------------------------------------------------------------------------
__global__ void pack_e_kernel(const float* __restrict__ emb,
                              uint4* __restrict__ ep4,
                              float* __restrict__ enorm,
                              int* __restrict__ counts) {
    int gid = blockIdx.x * 256 + threadIdx.x;      // 0..4095
    int code = gid >> 2, tq = gid & 3;             // tq: k-quarter (16 elems)
    const float* row = emb + (size_t)code * D + tq * 16;
    unsigned int hi[8], lo[8];
    float nrm = 0.f;
#pragma unroll
    for (int i = 0; i < 4; ++i) {
        float4 v = *reinterpret_cast<const float4*>(row + i * 4);
        nrm += v.x * v.x + v.y * v.y + v.z * v.z + v.w * v.w;
        float f[4] = {v.x, v.y, v.z, v.w};
        unsigned short hh[4], ll[4];
#pragma unroll
        for (int j = 0; j < 4; ++j) {
            hh[j] = bf16_rne(f[j]);
            ll[j] = bf16_rne(f[j] - bf16_f32(hh[j]));
        }
        hi[i * 2 + 0] = (unsigned)hh[0] | ((unsigned)hh[1] << 16);
        hi[i * 2 + 1] = (unsigned)hh[2] | ((unsigned)hh[3] << 16);
        lo[i * 2 + 0] = (unsigned)ll[0] | ((unsigned)ll[1] << 16);
        lo[i * 2 + 1] = (unsigned)ll[2] | ((unsigned)ll[3] << 16);
    }
    const int ct = code >> 6, g = (code >> 4) & 3, c = code & 15;
#pragma unroll
    for (int h = 0; h < 2; ++h) {
        int gran = 2 * tq + h;               // 0..7
        int bg = gran >> 2, q = gran & 3;
        ep4[(size_t)(ct * 16 + g * 4 + bg) * 64 + q * 16 + c] =
            make_uint4(hi[h * 4], hi[h * 4 + 1], hi[h * 4 + 2], hi[h * 4 + 3]);
        int granl = 8 + gran;                // lo: bg 2..3
        bg = granl >> 2; q = granl & 3;
        ep4[(size_t)(ct * 16 + g * 4 + bg) * 64 + q * 16 + c] =
            make_uint4(lo[h * 4], lo[h * 4 + 1], lo[h * 4 + 2], lo[h * 4 + 3]);
    }
    nrm += __shfl_xor(nrm, 1, 64);
    nrm += __shfl_xor(nrm, 2, 64);
    if (tq == 0) enorm[code] = nrm;
    if (gid < K) counts[gid] = 0;
}

// ---------------------------------------------------------------------------
// Kernel B: streaming MFMA VQ, M=32 vectors/wave (2x B-reuse vs R12/R13 —
// halves the L2 codebook traffic that bounded those rounds at ~21 TB/s).
//  - Block = 256 thr = 4 waves: (wp = vector pair-group of 32 vecs) x
//    (kh = K-half of 512 codes). Barrier-free K-loop; B-frags stream from
//    the L2-resident packed codebook (coalesced 1 KB/instr).
//  - A = 8 named s16x8 (32 VGPRs); __launch_bounds__(256,4) caps 128 VGPR.
//  - acc init = -enc/2 (C operand); argMAX of score = dot - enc/2
//    (dist = -2*score: exact monotone map, exact tie equivalence).
//  - Epilogue: kh=0 publishes packed u64 keys (monotone-score:1023-code) to
//    LDS; barrier; kh=1 combines (bit-exact first-occurrence ties) + counts
//    atomics; barrier; all 256 threads write winning rows (exact fp32).
// C-layout: col(code)=lane&15, row(vec)=(lane>>4)*4+reg (m89-verified).
// ---------------------------------------------------------------------------
__global__ void __launch_bounds__(256, 4)
vq_kernel(const float* __restrict__ x,
          const float* __restrict__ emb,
          const uint4* __restrict__ ep4,
          const float* __restrict__ enormp,
          int* __restrict__ counts,
          float* __restrict__ out) {
    __shared__ unsigned long long keys[64];
    __shared__ int bks[64];

    const int t    = threadIdx.x;
    const int w    = t >> 6;
    const int wp   = w >> 1;                  // vector group of 32: 0..1
    const int kh   = w & 1;                   // K-half
    const int lane = t & 63;
    const int q    = lane >> 4;
    const int c    = lane & 15;
    const int vb   = blockIdx.x * 64;

    // ---- A-frags: 32 vectors/wave, bf16 hi/lo, 8 named s16x8 (32 VGPRs) ----
    s16x8 Ah00, Ah01, Ah10, Ah11, Al00, Al01, Al10, Al11;
#define LOAD_A(mt, h, AH, AL)                                                  \
    {                                                                          \
        const float* xr = x + (size_t)(vb + wp * 32 + (mt) * 16 + c) * D       \
                            + (h) * 32 + q * 8;                                \
        float4 u0 = *reinterpret_cast<const float4*>(xr);                      \
        float4 u1 = *reinterpret_cast<const float4*>(xr + 4);                  \
        float f[8] = {u0.x, u0.y, u0.z, u0.w, u1.x, u1.y, u1.z, u1.w};         \
        s16x8 hiv, lov;                                                        \
        _Pragma("unroll") for (int j = 0; j < 8; ++j) {                        \
            unsigned short hb = bf16_rne(f[j]);                                \
            hiv[j] = (short)hb;                                                \
            lov[j] = (short)bf16_rne(f[j] - bf16_f32(hb));                     \
        }                                                                      \
        AH = hiv; AL = lov;                                                    \
    }
    LOAD_A(0, 0, Ah00, Al00)
    LOAD_A(0, 1, Ah01, Al01)
    LOAD_A(1, 0, Ah10, Al10)
    LOAD_A(1, 1, Ah11, Al11)
#undef LOAD_A

    float best[8];
    int   bk_[8];
#pragma unroll
    for (int s = 0; s < 8; ++s) { best[s] = -3.4e38f; bk_[s] = 0; }

    const uint4* epb = ep4 + (size_t)(kh * 128) * 64;   // this half's chunks
    const float* enb = enormp + kh * 512;

#pragma unroll 2
    for (int cg = 0; cg < 32; ++cg) {          // 16 codes per cg
        s16x8 Bh0 = *reinterpret_cast<const s16x8*>(&epb[(cg * 4 + 0) * 64 + lane]);
        s16x8 Bh1 = *reinterpret_cast<const s16x8*>(&epb[(cg * 4 + 1) * 64 + lane]);
        s16x8 Bl0 = *reinterpret_cast<const s16x8*>(&epb[(cg * 4 + 2) * 64 + lane]);
        s16x8 Bl1 = *reinterpret_cast<const s16x8*>(&epb[(cg * 4 + 3) * 64 + lane]);
        float enc = enb[cg * 16 + c];

        const float e2 = -0.5f * enc;
        f32x4 acc0 = (f32x4){e2, e2, e2, e2};
        f32x4 acc1 = (f32x4){e2, e2, e2, e2};
        acc0 = MFMA(Ah00, Bh0, acc0);  acc1 = MFMA(Ah10, Bh0, acc1);
        acc0 = MFMA(Ah01, Bh1, acc0);  acc1 = MFMA(Ah11, Bh1, acc1);
        acc0 = MFMA(Ah00, Bl0, acc0);  acc1 = MFMA(Ah10, Bl0, acc1);
        acc0 = MFMA(Ah01, Bl1, acc0);  acc1 = MFMA(Ah11, Bl1, acc1);
        acc0 = MFMA(Al00, Bh0, acc0);  acc1 = MFMA(Al10, Bh0, acc1);
        acc0 = MFMA(Al01, Bh1, acc0);  acc1 = MFMA(Al11, Bh1, acc1);

        const int codeG = kh * 512 + cg * 16 + c;
#pragma unroll
        for (int r = 0; r < 4; ++r) {
            if (acc0[r] > best[r])     { best[r] = acc0[r];     bk_[r] = codeG; }
            if (acc1[r] > best[4 + r]) { best[4 + r] = acc1[r]; bk_[4 + r] = codeG; }
        }
    }

    // ---- reduce over the 16 code-columns (max score; tie -> smaller idx) ----
#pragma unroll
    for (int m = 1; m <= 8; m <<= 1)
#pragma unroll
        for (int s = 0; s < 8; ++s) {
            float ob = __shfl_xor(best[s], m, 64);
            int   ok = __shfl_xor(bk_[s], m, 64);
            if (ob > best[s] || (ob == best[s] && ok < bk_[s])) {
                best[s] = ob; bk_[s] = ok;
            }
        }

    // packed key: (monotone_u32(score) << 32) | (1023 - code)
    unsigned long long mykey[8];
#pragma unroll
    for (int s = 0; s < 8; ++s) {
        unsigned u = __float_as_uint(best[s]);
        u = ((int)u < 0) ? ~u : (u | 0x80000000u);
        mykey[s] = ((unsigned long long)u << 32) | (unsigned)(1023 - bk_[s]);
    }

    if (kh == 0 && c == 0) {
#pragma unroll
        for (int s = 0; s < 8; ++s) {
            int mt = s >> 2, r = s & 3;
            keys[wp * 32 + mt * 16 + q * 4 + r] = mykey[s];
        }
    }
    __syncthreads();
    if (kh == 1 && c == 0) {
#pragma unroll
        for (int s = 0; s < 8; ++s) {
            int mt = s >> 2, r = s & 3;
            int lv = wp * 32 + mt * 16 + q * 4 + r;
            unsigned long long k0 = keys[lv];
            unsigned long long kw = (mykey[s] > k0) ? mykey[s] : k0;
            int code = 1023 - (int)(kw & 0xFFFFFFFFu);
            bks[lv] = code;
            atomicAdd(&counts[code], 1);
        }
    }
    __syncthreads();

    // ---- all 256 threads: write winning rows -> out (exact fp32) ----
    {
        int vec = t >> 2, part = t & 3;          // 4 threads per vector
        int kk = bks[vec];
        const float4* src = reinterpret_cast<const float4*>(emb + (size_t)kk * D) + part * 4;
        float4* dst = reinterpret_cast<float4*>(out + (size_t)(vb + vec) * D) + part * 4;
#pragma unroll
        for (int j = 0; j < 4; ++j) dst[j] = src[j];
    }
}

// ---------------------------------------------------------------------------
// Kernel C: perplexity = exp(-sum p log(p+eps)), p = counts/N. 256 threads.
// ---------------------------------------------------------------------------
__global__ void perplexity_kernel(const int* __restrict__ counts,
                                  float* __restrict__ outp) {
    int t = threadIdx.x;
    float s = 0.f;
#pragma unroll
    for (int i = 0; i < 4; ++i) {
        float p = (float)counts[t + i * 256] * (1.0f / (float)N_VEC);
        s += p * logf(p + VQ_EPS);
    }
#pragma unroll
    for (int m = 1; m < 64; m <<= 1) s += __shfl_xor(s, m, 64);
    __shared__ float ws[4];
    if ((t & 63) == 0) ws[t >> 6] = s;
    __syncthreads();
    if (t == 0) *outp = expf(-(ws[0] + ws[1] + ws[2] + ws[3]));
}

// ---------------------------------------------------------------------------
extern "C" void kernel_launch(void* const* d_in, const int* in_sizes, int n_in,
                              void* d_out, int out_size, void* d_ws, size_t ws_size,
                              hipStream_t stream) {
    const float* x   = (const float*)d_in[0];   // [65536, 64] fp32
    const float* emb = (const float*)d_in[1];   // [1024, 64] fp32
    float* out = (float*)d_out;                 // 4194304 quantized + 1 perplexity

    uint4* ep     = (uint4*)d_ws;                                      // 256 KB packed
    float* enorm  = (float*)((char*)d_ws + (size_t)K * 128 * 2);       // 4 KB
    int*   counts = (int*)((char*)enorm + K * sizeof(float));          // 4 KB

    pack_e_kernel<<<16, 256, 0, stream>>>(emb, ep, enorm, counts);
    vq_kernel<<<N_VEC / 64, 256, 0, stream>>>(x, emb, ep, enorm, counts, out);
    perplexity_kernel<<<1, 256, 0, stream>>>(counts, out + (size_t)N_VEC * D);
}